// Round 1
// baseline (252.435 us; speedup 1.0000x reference)
//
#include <hip/hip_runtime.h>
#include <hip/hip_bf16.h>

typedef float  f32x4  __attribute__((ext_vector_type(4)));
typedef __bf16 bf16x8 __attribute__((ext_vector_type(8)));

#define MFMA16(A,B,C) __builtin_amdgcn_mfma_f32_16x16x32_bf16((A),(B),(C),0,0,0)

constexpr int BN = 16, HN = 8, LN = 128, DN = 64;
constexpr size_t OUT0 = (size_t)BN * HN * BN * LN * DN;   // 16,777,216 floats (O), attn follows

// load 8 consecutive floats, split into bf16 hi + lo (x ~= hi + lo, err ~2^-16 rel)
__device__ __forceinline__ void load8_cvt(const float* __restrict__ p,
                                          bf16x8& hi, bf16x8& lo) {
  float f[8];
  *(float4*)&f[0] = *(const float4*)(p);
  *(float4*)&f[4] = *(const float4*)(p + 4);
#pragma unroll
  for (int i = 0; i < 8; ++i) {
    __bf16 h = (__bf16)f[i];
    hi[i] = h;
    lo[i] = (__bf16)(f[i] - (float)h);
  }
}

__global__ __launch_bounds__(256, 2) void isa_attn_kernel(
    const float* __restrict__ Q, const float* __restrict__ K,
    const float* __restrict__ V, const int* __restrict__ M,
    float* __restrict__ out)
{
  // LDS: V^T (for k-contiguous B-fragments of PV) + P half-tile (C->A layout round trip)
  __shared__ float VT[DN][LN + 4];   // VT[d][j] = V[j][d], pad 4 floats vs bank stride
  __shared__ float P [LN][64 + 4];   // attn weights, one 64-col half at a time

  const int bid = blockIdx.x;
  const int b = bid >> 7;            // (b,h,c) matches output flat order
  const int h = (bid >> 4) & 7;
  const int c = bid & 15;

  const float* Qp = Q + (size_t)(b * HN + h) * (LN * DN);
  const float* Kp = K + (size_t)(h * BN + c) * (LN * DN);
  const float* Vp = V + (size_t)(h * BN + c) * (LN * DN);
  const int*   Mp = M + (size_t)b * (LN * LN);
  float* Op = out + (size_t)bid * (LN * DN);
  float* Wp = out + OUT0 + (size_t)bid * (LN * LN);

  const int t    = threadIdx.x;
  const int lane = t & 63;
  const int wave = t >> 6;           // wave w owns S/O rows [32w, 32w+32)
  const int quad = lane >> 4;
  const int l16  = lane & 15;
  const int row0 = wave * 32;

  // ---- stage V^T into LDS (coalesced float4 reads, scalar transposed writes) ----
#pragma unroll
  for (int it = 0; it < 8; ++it) {
    int idx4 = t + it * 256;         // 2048 float4s = 128x64 floats
    int j  = idx4 >> 4;
    int d0 = (idx4 & 15) * 4;
    float4 v = ((const float4*)Vp)[idx4];
    VT[d0 + 0][j] = v.x; VT[d0 + 1][j] = v.y;
    VT[d0 + 2][j] = v.z; VT[d0 + 3][j] = v.w;
  }

  // ---- Q A-fragments direct from global: A[m=l16][k=quad*8+j], rt=row-tile, kt=D-chunk ----
  bf16x8 qhi[2][2], qlo[2][2];
#pragma unroll
  for (int rt = 0; rt < 2; ++rt)
#pragma unroll
    for (int kt = 0; kt < 2; ++kt)
      load8_cvt(Qp + (row0 + rt * 16 + l16) * DN + kt * 32 + quad * 8,
                qhi[rt][kt], qlo[rt][kt]);

  // ---- S = Q K^T (3-term bf16 split per step) ----
  f32x4 acc[2][8];
#pragma unroll
  for (int rt = 0; rt < 2; ++rt)
#pragma unroll
    for (int ct = 0; ct < 8; ++ct)
      acc[rt][ct] = (f32x4){0.f, 0.f, 0.f, 0.f};

#pragma unroll
  for (int ct = 0; ct < 8; ++ct) {
#pragma unroll
    for (int kt = 0; kt < 2; ++kt) {
      bf16x8 khi, klo;  // B-frag: B[k][n] = K[n=ct*16+l16][k], k-contiguous per lane
      load8_cvt(Kp + (ct * 16 + l16) * DN + kt * 32 + quad * 8, khi, klo);
#pragma unroll
      for (int rt = 0; rt < 2; ++rt) {
        acc[rt][ct] = MFMA16(qhi[rt][kt], khi, acc[rt][ct]);
        acc[rt][ct] = MFMA16(qlo[rt][kt], khi, acc[rt][ct]);
        acc[rt][ct] = MFMA16(qhi[rt][kt], klo, acc[rt][ct]);
      }
    }
  }

  // ---- mask + scale + softmax; rows are quad-local (quad q owns rows q*4+reg) ----
#pragma unroll
  for (int rt = 0; rt < 2; ++rt) {
    int mv[8][4];
#pragma unroll
    for (int ct = 0; ct < 8; ++ct)
#pragma unroll
      for (int r = 0; r < 4; ++r)
        mv[ct][r] = Mp[(row0 + rt * 16 + quad * 4 + r) * LN + ct * 16 + l16];
#pragma unroll
    for (int r = 0; r < 4; ++r) {
      float s[8];
      float mx = -3.0e38f;
#pragma unroll
      for (int ct = 0; ct < 8; ++ct) {
        s[ct] = (mv[ct][r] != 0) ? acc[rt][ct][r] * 0.125f : -1.0e9f;
        mx = fmaxf(mx, s[ct]);
      }
      mx = fmaxf(mx, __shfl_xor(mx, 1));
      mx = fmaxf(mx, __shfl_xor(mx, 2));
      mx = fmaxf(mx, __shfl_xor(mx, 4));
      mx = fmaxf(mx, __shfl_xor(mx, 8));
      float sum = 0.f;
#pragma unroll
      for (int ct = 0; ct < 8; ++ct) { s[ct] = __expf(s[ct] - mx); sum += s[ct]; }
      sum += __shfl_xor(sum, 1);
      sum += __shfl_xor(sum, 2);
      sum += __shfl_xor(sum, 4);
      sum += __shfl_xor(sum, 8);
      float inv = __builtin_amdgcn_rcpf(sum);
      inv = inv * (2.0f - sum * inv);          // one NR step -> ~fp32 exact
#pragma unroll
      for (int ct = 0; ct < 8; ++ct) acc[rt][ct][r] = s[ct] * inv;
    }
  }

  __syncthreads();   // VT staged by all waves before any B-frag read

  f32x4 oacc[2][4];
#pragma unroll
  for (int rt = 0; rt < 2; ++rt)
#pragma unroll
    for (int nt = 0; nt < 4; ++nt)
      oacc[rt][nt] = (f32x4){0.f, 0.f, 0.f, 0.f};

  // ---- per column-half: P -> LDS (C layout), attn -> global, partial PV ----
#pragma unroll
  for (int half = 0; half < 2; ++half) {
    // scatter this wave's 32x64 weights into its own P rows (no cross-wave access)
#pragma unroll
    for (int rt = 0; rt < 2; ++rt)
#pragma unroll
      for (int c4 = 0; c4 < 4; ++c4)
#pragma unroll
        for (int r = 0; r < 4; ++r)
          P[row0 + rt * 16 + quad * 4 + r][c4 * 16 + l16] = acc[rt][half * 4 + c4][r];

    // coalesced attn-weight write from LDS
#pragma unroll
    for (int e = 0; e < 8; ++e) {
      int idx = e * 64 + lane;               // 512 float4 = 32 rows x 16
      int r  = idx >> 4;
      int c4 = (idx & 15) * 4;
      float4 v = *(const float4*)&P[row0 + r][c4];
      *(float4*)&Wp[(size_t)(row0 + r) * LN + half * 64 + c4] = v;
    }

    // O += P_half * V_half  (contraction j over this half's 64 cols)
#pragma unroll
    for (int jt = 0; jt < 2; ++jt) {
      bf16x8 phi[2], plo[2];
#pragma unroll
      for (int rt = 0; rt < 2; ++rt)        // A-frag: P[m=l16][k=quad*8+j], fp32->hi/lo
        load8_cvt(&P[row0 + rt * 16 + l16][jt * 32 + quad * 8], phi[rt], plo[rt]);
#pragma unroll
      for (int nt = 0; nt < 4; ++nt) {
        bf16x8 vhi, vlo;                    // B-frag: VT[n=nt*16+l16][k], k-contiguous
        load8_cvt(&VT[nt * 16 + l16][half * 64 + jt * 32 + quad * 8], vhi, vlo);
#pragma unroll
        for (int rt = 0; rt < 2; ++rt) {
          oacc[rt][nt] = MFMA16(phi[rt], vhi, oacc[rt][nt]);
          oacc[rt][nt] = MFMA16(plo[rt], vhi, oacc[rt][nt]);
          oacc[rt][nt] = MFMA16(phi[rt], vlo, oacc[rt][nt]);
        }
      }
    }
  }

  // ---- store O from C layout (64B row segments) ----
#pragma unroll
  for (int rt = 0; rt < 2; ++rt)
#pragma unroll
    for (int nt = 0; nt < 4; ++nt)
#pragma unroll
      for (int r = 0; r < 4; ++r)
        Op[(row0 + rt * 16 + quad * 4 + r) * DN + nt * 16 + l16] = oacc[rt][nt][r];
}

extern "C" void kernel_launch(void* const* d_in, const int* in_sizes, int n_in,
                              void* d_out, int out_size, void* d_ws, size_t ws_size,
                              hipStream_t stream) {
  const float* Q = (const float*)d_in[0];
  const float* K = (const float*)d_in[1];
  const float* V = (const float*)d_in[2];
  const int*   M = (const int*)d_in[3];
  float* out = (float*)d_out;
  isa_attn_kernel<<<dim3(BN * HN * BN), dim3(256), 0, stream>>>(Q, K, V, M, out);
}

// Round 2
// 249.297 us; speedup vs baseline: 1.0126x; 1.0126x over previous
//
#include <hip/hip_runtime.h>
#include <hip/hip_bf16.h>

typedef float  f32x4  __attribute__((ext_vector_type(4)));
typedef __bf16 bf16x8 __attribute__((ext_vector_type(8)));
typedef __bf16 bf16x2 __attribute__((ext_vector_type(2)));

#define MFMA16(A,B,C) __builtin_amdgcn_mfma_f32_16x16x32_bf16((A),(B),(C),0,0,0)

constexpr int BN = 16, HN = 8, LN = 128, DN = 64;
constexpr size_t OUT0 = (size_t)BN * HN * BN * LN * DN;   // O elements; attn follows

// 8 consecutive floats -> bf16 hi + lo (x ~= hi+lo), with pre-scale
__device__ __forceinline__ void load8_split(const float* __restrict__ p, float scale,
                                            bf16x8& hi, bf16x8& lo) {
  float f[8];
  *(float4*)&f[0] = *(const float4*)(p);
  *(float4*)&f[4] = *(const float4*)(p + 4);
#pragma unroll
  for (int i = 0; i < 8; ++i) {
    float x = f[i] * scale;
    __bf16 h = (__bf16)x;
    hi[i] = h;
    lo[i] = (__bf16)(x - (float)h);
  }
}

// 8 consecutive floats -> bf16 hi only
__device__ __forceinline__ void load8_hi(const float* __restrict__ p, bf16x8& hi) {
  float f[8];
  *(float4*)&f[0] = *(const float4*)(p);
  *(float4*)&f[4] = *(const float4*)(p + 4);
#pragma unroll
  for (int i = 0; i < 8; ++i) hi[i] = (__bf16)f[i];
}

// 8 consecutive floats from LDS -> hi/lo split (no scale)
__device__ __forceinline__ void lds8_split(const float* p, bf16x8& hi, bf16x8& lo) {
  float f[8];
  *(float4*)&f[0] = *(const float4*)(p);
  *(float4*)&f[4] = *(const float4*)(p + 4);
#pragma unroll
  for (int i = 0; i < 8; ++i) {
    __bf16 h = (__bf16)f[i];
    hi[i] = h;
    lo[i] = (__bf16)(f[i] - (float)h);
  }
}

__global__ __launch_bounds__(256, 3) void isa_attn_kernel(
    const float* __restrict__ Q, const float* __restrict__ K,
    const float* __restrict__ V, const int* __restrict__ M,
    float* __restrict__ out)
{
  // 17408 B: V^T in bf16 (hi only); row stride 136*2=272 B (16B aligned)
  __shared__ __bf16 VT[DN][136];
  // 34816 B: P transform buffer, half-width (64 cols + pad), wave-private rows
  __shared__ float P[LN][68];
  // total 52224 B -> 3 blocks/CU

  const int bid = blockIdx.x;
  const int b = bid >> 7;
  const int h = (bid >> 4) & 7;
  const int c = bid & 15;

  const float* Qp = Q + (size_t)(b * HN + h) * (LN * DN);
  const float* Kp = K + (size_t)(h * BN + c) * (LN * DN);
  const float* Vp = V + (size_t)(h * BN + c) * (LN * DN);
  const int*   Mp = M + (size_t)b * (LN * LN);
  float* Op = out + (size_t)bid * (LN * DN);
  float* Wp = out + OUT0 + (size_t)bid * (LN * LN);

  const int t    = threadIdx.x;
  const int lane = t & 63;
  const int wave = t >> 6;           // wave owns S/O rows [32w, 32w+32)
  const int quad = lane >> 4;
  const int l16  = lane & 15;
  const int row0 = wave * 32;

  // ---- stage V^T (bf16) into LDS: thread does 2 rows x 4 d, packs column pairs ----
#pragma unroll
  for (int it = 0; it < 4; ++it) {
    int idx = t + it * 256;          // 1024 units
    int j2  = idx >> 4;              // column pair 0..63
    int d0  = (idx & 15) * 4;
    float4 a = *(const float4*)(Vp + (2 * j2) * DN + d0);
    float4 bb = *(const float4*)(Vp + (2 * j2 + 1) * DN + d0);
    const float* af = (const float*)&a;
    const float* bf = (const float*)&bb;
#pragma unroll
    for (int w = 0; w < 4; ++w)
      *(bf16x2*)&VT[d0 + w][2 * j2] = (bf16x2){(__bf16)af[w], (__bf16)bf[w]};
  }

  // ---- Q A-fragments (pre-scaled by 1/8, hi/lo split) ----
  bf16x8 qhi[2][2], qlo[2][2];
#pragma unroll
  for (int rt = 0; rt < 2; ++rt)
#pragma unroll
    for (int kt = 0; kt < 2; ++kt)
      load8_split(Qp + (row0 + rt * 16 + l16) * DN + kt * 32 + quad * 8, 0.125f,
                  qhi[rt][kt], qlo[rt][kt]);

  // ---- S = (Qhi+Qlo) Khi^T : 2 MFMA per tile-step ----
  f32x4 acc[2][8];
#pragma unroll
  for (int rt = 0; rt < 2; ++rt)
#pragma unroll
    for (int ct = 0; ct < 8; ++ct)
      acc[rt][ct] = (f32x4){0.f, 0.f, 0.f, 0.f};

#pragma unroll
  for (int ct = 0; ct < 8; ++ct) {
#pragma unroll
    for (int kt = 0; kt < 2; ++kt) {
      bf16x8 kh;
      load8_hi(Kp + (ct * 16 + l16) * DN + kt * 32 + quad * 8, kh);
#pragma unroll
      for (int rt = 0; rt < 2; ++rt) {
        acc[rt][ct] = MFMA16(qhi[rt][kt], kh, acc[rt][ct]);
        acc[rt][ct] = MFMA16(qlo[rt][kt], kh, acc[rt][ct]);
      }
    }
  }

  // ---- softmax (mask as post-exp multiplier; exact — common shift cancels) ----
  // also writes attn weights directly (fp32 exact, 64B row segments)
#pragma unroll
  for (int rt = 0; rt < 2; ++rt) {
#pragma unroll
    for (int r = 0; r < 4; ++r) {
      int row = row0 + rt * 16 + quad * 4 + r;
      const int* mrow = Mp + (size_t)row * LN + l16;
      float*     wrow = Wp + (size_t)row * LN + l16;
      float mf[8];
#pragma unroll
      for (int ct = 0; ct < 8; ++ct) mf[ct] = (float)mrow[ct * 16];
      float mx = -3.0e38f;
#pragma unroll
      for (int ct = 0; ct < 8; ++ct) mx = fmaxf(mx, acc[rt][ct][r]);
      mx = fmaxf(mx, __shfl_xor(mx, 1));
      mx = fmaxf(mx, __shfl_xor(mx, 2));
      mx = fmaxf(mx, __shfl_xor(mx, 4));
      mx = fmaxf(mx, __shfl_xor(mx, 8));
      float s[8];
      float sum = 0.f;
#pragma unroll
      for (int ct = 0; ct < 8; ++ct) {
        s[ct] = __expf(acc[rt][ct][r] - mx) * mf[ct];
        sum += s[ct];
      }
      sum += __shfl_xor(sum, 1);
      sum += __shfl_xor(sum, 2);
      sum += __shfl_xor(sum, 4);
      sum += __shfl_xor(sum, 8);
      float inv = __builtin_amdgcn_rcpf(sum);
      inv = inv * (2.0f - sum * inv);          // NR -> ~fp32 exact
#pragma unroll
      for (int ct = 0; ct < 8; ++ct) {
        float w = s[ct] * inv;
        acc[rt][ct][r] = w;
        wrow[ct * 16] = w;                     // attn output, fp32 exact
      }
    }
  }

  __syncthreads();   // VT staged by all waves before any B-frag read

  f32x4 oacc[2][4];
#pragma unroll
  for (int rt = 0; rt < 2; ++rt)
#pragma unroll
    for (int nt = 0; nt < 4; ++nt)
      oacc[rt][nt] = (f32x4){0.f, 0.f, 0.f, 0.f};

  // ---- PV per column-half: scatter P (wave-private rows, no barrier), MFMA ----
#pragma unroll
  for (int half = 0; half < 2; ++half) {
#pragma unroll
    for (int rt = 0; rt < 2; ++rt)
#pragma unroll
      for (int c4 = 0; c4 < 4; ++c4)
#pragma unroll
        for (int r = 0; r < 4; ++r)
          P[row0 + rt * 16 + quad * 4 + r][c4 * 16 + l16] = acc[rt][half * 4 + c4][r];
    // same-wave lanes wrote the rows we read: compiler inserts lgkmcnt wait (LDS dep)

#pragma unroll
    for (int jt = 0; jt < 2; ++jt) {
      bf16x8 phi[2], plo[2];
#pragma unroll
      for (int rt = 0; rt < 2; ++rt)   // A-frag: P[m=l16][k=quad*8+j], fp32 -> hi/lo
        lds8_split(&P[row0 + rt * 16 + l16][jt * 32 + quad * 8], phi[rt], plo[rt]);
#pragma unroll
      for (int nt = 0; nt < 4; ++nt) {
        bf16x8 vh = *(const bf16x8*)&VT[nt * 16 + l16][half * 64 + jt * 32 + quad * 8];
#pragma unroll
        for (int rt = 0; rt < 2; ++rt) {
          oacc[rt][nt] = MFMA16(phi[rt], vh, oacc[rt][nt]);
          oacc[rt][nt] = MFMA16(plo[rt], vh, oacc[rt][nt]);
        }
      }
    }
  }

  // ---- store O ----
#pragma unroll
  for (int rt = 0; rt < 2; ++rt)
#pragma unroll
    for (int nt = 0; nt < 4; ++nt)
#pragma unroll
      for (int r = 0; r < 4; ++r)
        Op[(row0 + rt * 16 + quad * 4 + r) * DN + nt * 16 + l16] = oacc[rt][nt][r];
}

extern "C" void kernel_launch(void* const* d_in, const int* in_sizes, int n_in,
                              void* d_out, int out_size, void* d_ws, size_t ws_size,
                              hipStream_t stream) {
  const float* Q = (const float*)d_in[0];
  const float* K = (const float*)d_in[1];
  const float* V = (const float*)d_in[2];
  const int*   M = (const int*)d_in[3];
  isa_attn_kernel<<<dim3(BN * HN * BN), dim3(256), 0, stream>>>(Q, K, V, M, (float*)d_out);
}

// Round 3
// 238.378 us; speedup vs baseline: 1.0590x; 1.0458x over previous
//
#include <hip/hip_runtime.h>
#include <hip/hip_bf16.h>

typedef float  f32x4  __attribute__((ext_vector_type(4)));
typedef __bf16 bf16x8 __attribute__((ext_vector_type(8)));

#define MFMA16(A,B,C) __builtin_amdgcn_mfma_f32_16x16x32_bf16((A),(B),(C),0,0,0)

constexpr int BN = 16, HN = 8, LN = 128, DN = 64;
constexpr size_t OUT0 = (size_t)BN * HN * BN * LN * DN;  // O elements; attn follows

constexpr int KTS = 72;   // KT row stride (bf16) = 144 B (16B-mult; uniform bank groups)
constexpr int VTS = 136;  // VT row stride (bf16) = 272 B
constexpr int PS  = 36;   // P  row stride (fp32) = 144 B

// 8 consecutive floats -> bf16 hi + lo with pre-scale
__device__ __forceinline__ void load8_split(const float* __restrict__ p, float scale,
                                            bf16x8& hi, bf16x8& lo) {
  float f[8];
  *(float4*)&f[0] = *(const float4*)(p);
  *(float4*)&f[4] = *(const float4*)(p + 4);
#pragma unroll
  for (int i = 0; i < 8; ++i) {
    float x = f[i] * scale;
    __bf16 h = (__bf16)x;
    hi[i] = h;
    lo[i] = (__bf16)(x - (float)h);
  }
}

// 8 consecutive floats from LDS -> hi/lo split
__device__ __forceinline__ void lds8_split(const float* p, bf16x8& hi, bf16x8& lo) {
  float f[8];
  *(float4*)&f[0] = *(const float4*)(p);
  *(float4*)&f[4] = *(const float4*)(p + 4);
#pragma unroll
  for (int i = 0; i < 8; ++i) {
    __bf16 h = (__bf16)f[i];
    hi[i] = h;
    lo[i] = (__bf16)(f[i] - (float)h);
  }
}

__global__ __launch_bounds__(256, 3) void isa_attn_kernel(
    const float* __restrict__ Q, const float* __restrict__ K,
    const float* __restrict__ V, const int* __restrict__ M,
    float* __restrict__ out)
{
  __shared__ __bf16 KT[LN * KTS];  // 18432 B  K as bf16, row-major [n][k]
  __shared__ __bf16 VT[DN * VTS];  // 17408 B  V^T as bf16 [d][j]
  __shared__ float  P [LN * PS];   // 18432 B  quarter-width transform buffer
  // total 54272 B -> 3 blocks/CU

  const int bid = blockIdx.x;
  // XCD swizzle: dispatch round-robins bid%8 across XCDs; make each XCD own one h
  // -> per-XCD L2 footprint: K,V(h,*) 1.05MB + Q(*,h) 2.1MB + mask 1MB ~= 4MB L2.
  const int w = (bid & 7) * 256 + (bid >> 3);
  const int h = w >> 8;
  const int c = (w >> 4) & 15;
  const int b = w & 15;

  const float* Qp = Q + (size_t)(b * HN + h) * (LN * DN);
  const float* Kp = K + (size_t)(h * BN + c) * (LN * DN);
  const float* Vp = V + (size_t)(h * BN + c) * (LN * DN);
  const int*   Mp = M + (size_t)b * (LN * LN);
  float* Op = out + (size_t)((b * HN + h) * BN + c) * (LN * DN);
  float* Wp = out + OUT0 + (size_t)((b * HN + h) * BN + c) * (LN * LN);

  const int t    = threadIdx.x;
  const int lane = t & 63;
  const int wid  = t >> 6;          // wave owns S/O rows [32w, 32w+32)
  const int quad = lane >> 4;
  const int l16  = lane & 15;
  const int row0 = wid * 32;

  // ---- stage K -> KT (bf16): conflict-free ds_write_b128 ----
#pragma unroll
  for (int it = 0; it < 4; ++it) {
    int idx = t + it * 256;         // 1024 units: n = idx>>3, k0 = (idx&7)*8
    int n  = idx >> 3;
    int k0 = (idx & 7) * 8;
    float4 a0 = *(const float4*)(Kp + n * DN + k0);
    float4 a1 = *(const float4*)(Kp + n * DN + k0 + 4);
    bf16x8 kk;
    kk[0] = (__bf16)a0.x; kk[1] = (__bf16)a0.y; kk[2] = (__bf16)a0.z; kk[3] = (__bf16)a0.w;
    kk[4] = (__bf16)a1.x; kk[5] = (__bf16)a1.y; kk[6] = (__bf16)a1.z; kk[7] = (__bf16)a1.w;
    *(bf16x8*)&KT[n * KTS + k0] = kk;
  }

  // ---- stage V^T -> VT (bf16): 8-row register transpose, ds_write_b128 ----
  {
    int j8 = t >> 4;                // 0..15 -> j block of 8
    int d0 = (t & 15) * 4;
    float4 vv[8];
#pragma unroll
    for (int r = 0; r < 8; ++r)
      vv[r] = *(const float4*)(Vp + (j8 * 8 + r) * DN + d0);
#pragma unroll
    for (int dw = 0; dw < 4; ++dw) {
      bf16x8 col;
#pragma unroll
      for (int r = 0; r < 8; ++r)
        col[r] = (__bf16)(((const float*)&vv[r])[dw]);
      *(bf16x8*)&VT[(d0 + dw) * VTS + j8 * 8] = col;
    }
  }

  // ---- Q A-fragments direct from global (pre-scaled, hi/lo) — overlaps staging ----
  bf16x8 qhi[2][2], qlo[2][2];
#pragma unroll
  for (int rt = 0; rt < 2; ++rt)
#pragma unroll
    for (int kt = 0; kt < 2; ++kt)
      load8_split(Qp + (row0 + rt * 16 + l16) * DN + kt * 32 + quad * 8, 0.125f,
                  qhi[rt][kt], qlo[rt][kt]);

  __syncthreads();   // the only barrier: staging complete

  // ---- S = (Qhi+Qlo) Khi^T; B-frag = one ds_read_b128 from KT ----
  f32x4 acc[2][8];
#pragma unroll
  for (int rt = 0; rt < 2; ++rt)
#pragma unroll
    for (int ct = 0; ct < 8; ++ct)
      acc[rt][ct] = (f32x4){0.f, 0.f, 0.f, 0.f};

#pragma unroll
  for (int ct = 0; ct < 8; ++ct) {
#pragma unroll
    for (int kt = 0; kt < 2; ++kt) {
      bf16x8 kh = *(const bf16x8*)&KT[(ct * 16 + l16) * KTS + kt * 32 + quad * 8];
#pragma unroll
      for (int rt = 0; rt < 2; ++rt) {
        acc[rt][ct] = MFMA16(qhi[rt][kt], kh, acc[rt][ct]);
        acc[rt][ct] = MFMA16(qlo[rt][kt], kh, acc[rt][ct]);
      }
    }
  }

  // ---- softmax (mask as post-exp multiplier; common max shift cancels) ----
#pragma unroll
  for (int rt = 0; rt < 2; ++rt) {
#pragma unroll
    for (int r = 0; r < 4; ++r) {
      int row = row0 + rt * 16 + quad * 4 + r;
      const int* mrow = Mp + (size_t)row * LN + l16;
      float mf[8];
#pragma unroll
      for (int ct = 0; ct < 8; ++ct) mf[ct] = (float)mrow[ct * 16];
      float mx = -3.0e38f;
#pragma unroll
      for (int ct = 0; ct < 8; ++ct) mx = fmaxf(mx, acc[rt][ct][r]);
      mx = fmaxf(mx, __shfl_xor(mx, 1));
      mx = fmaxf(mx, __shfl_xor(mx, 2));
      mx = fmaxf(mx, __shfl_xor(mx, 4));
      mx = fmaxf(mx, __shfl_xor(mx, 8));
      float s[8];
      float sum = 0.f;
#pragma unroll
      for (int ct = 0; ct < 8; ++ct) {
        s[ct] = __expf(acc[rt][ct][r] - mx) * mf[ct];
        sum += s[ct];
      }
      sum += __shfl_xor(sum, 1);
      sum += __shfl_xor(sum, 2);
      sum += __shfl_xor(sum, 4);
      sum += __shfl_xor(sum, 8);
      float inv = __builtin_amdgcn_rcpf(sum);
      inv = inv * (2.0f - sum * inv);
#pragma unroll
      for (int ct = 0; ct < 8; ++ct) acc[rt][ct][r] = s[ct] * inv;
    }
  }

  f32x4 oacc[2][4];
#pragma unroll
  for (int rt = 0; rt < 2; ++rt)
#pragma unroll
    for (int nt = 0; nt < 4; ++nt)
      oacc[rt][nt] = (f32x4){0.f, 0.f, 0.f, 0.f};

  // ---- per column-quarter (32 cols): scatter P, coalesced attn store, PV ----
  // P rows are wave-private: no barriers needed (same-wave LDS dependences)
#pragma unroll
  for (int qu = 0; qu < 4; ++qu) {
    // scatter weights (C-layout) into P; 2-way bank aliasing only (free)
#pragma unroll
    for (int rt = 0; rt < 2; ++rt)
#pragma unroll
      for (int cc = 0; cc < 2; ++cc)
#pragma unroll
        for (int r = 0; r < 4; ++r)
          P[(row0 + rt * 16 + quad * 4 + r) * PS + cc * 16 + l16] =
              acc[rt][qu * 2 + cc][r];

    // coalesced attn-weight store (fp32 exact): 4 x float4 per lane
#pragma unroll
    for (int e = 0; e < 4; ++e) {
      int idx = e * 64 + lane;      // 256 float4 = 32 rows x 8
      int rl  = idx >> 3;
      int c4  = idx & 7;
      float4 v = *(const float4*)&P[(row0 + rl) * PS + c4 * 4];
      *(float4*)&Wp[(size_t)(row0 + rl) * LN + qu * 32 + c4 * 4] = v;
    }

    // O += P_quarter * V_quarter
    bf16x8 phi[2], plo[2];
#pragma unroll
    for (int rt = 0; rt < 2; ++rt)
      lds8_split(&P[(row0 + rt * 16 + l16) * PS + quad * 8], phi[rt], plo[rt]);
#pragma unroll
    for (int nt = 0; nt < 4; ++nt) {
      bf16x8 vh = *(const bf16x8*)&VT[(nt * 16 + l16) * VTS + qu * 32 + quad * 8];
#pragma unroll
      for (int rt = 0; rt < 2; ++rt) {
        oacc[rt][nt] = MFMA16(phi[rt], vh, oacc[rt][nt]);
        oacc[rt][nt] = MFMA16(plo[rt], vh, oacc[rt][nt]);
      }
    }
  }

  // ---- O: scatter to P (wave-private), then coalesced float4 store ----
#pragma unroll
  for (int hf = 0; hf < 2; ++hf) {
#pragma unroll
    for (int rt = 0; rt < 2; ++rt)
#pragma unroll
      for (int nn = 0; nn < 2; ++nn)
#pragma unroll
        for (int r = 0; r < 4; ++r)
          P[(row0 + rt * 16 + quad * 4 + r) * PS + nn * 16 + l16] =
              oacc[rt][hf * 2 + nn][r];
#pragma unroll
    for (int e = 0; e < 4; ++e) {
      int idx = e * 64 + lane;      // 256 float4 = 32 rows x 8
      int rl  = idx >> 3;
      int c4  = idx & 7;
      float4 v = *(const float4*)&P[(row0 + rl) * PS + c4 * 4];
      *(float4*)&Op[(size_t)(row0 + rl) * DN + hf * 32 + c4 * 4] = v;
    }
  }
}

extern "C" void kernel_launch(void* const* d_in, const int* in_sizes, int n_in,
                              void* d_out, int out_size, void* d_ws, size_t ws_size,
                              hipStream_t stream) {
  const float* Q = (const float*)d_in[0];
  const float* K = (const float*)d_in[1];
  const float* V = (const float*)d_in[2];
  const int*   M = (const int*)d_in[3];
  isa_attn_kernel<<<dim3(BN * HN * BN), dim3(256), 0, stream>>>(Q, K, V, M, (float*)d_out);
}